// Round 1
// baseline (243.983 us; speedup 1.0000x reference)
//
#include <hip/hip_runtime.h>
#include <hip/hip_bf16.h>
#include <stdint.h>

typedef unsigned short u16;
typedef unsigned int u32;
typedef float f32x4 __attribute__((ext_vector_type(4)));
typedef short bf16x8 __attribute__((ext_vector_type(8)));

#define MFMA(a, b, c) __builtin_amdgcn_mfma_f32_16x16x32_bf16((a), (b), (c), 0, 0, 0)

__device__ __forceinline__ void gll16(const void* g, void* lds) {
  __builtin_amdgcn_global_load_lds(
      (const __attribute__((address_space(1))) u32*)(uintptr_t)g,
      (__attribute__((address_space(3))) u32*)(uintptr_t)lds, 16, 0, 0);
}

__device__ __forceinline__ u16 f2b(float f) {
  union { __hip_bfloat16 h; u16 u; } cv;
  cv.h = __float2bfloat16(f);
  return cv.u;
}

// ---------------- fp32 -> bf16 elementwise (vectorized) ----------------
__global__ __launch_bounds__(256) void k_cvt(const float* __restrict__ in,
                                             u16* __restrict__ out, int n4) {
  int i = blockIdx.x * 256 + threadIdx.x;
  if (i >= n4) return;
  const float4 v = reinterpret_cast<const float4*>(in)[i];
  u32 lo = (u32)f2b(v.x) | ((u32)f2b(v.y) << 16);
  u32 hi = (u32)f2b(v.z) | ((u32)f2b(v.w) << 16);
  reinterpret_cast<uint2*>(out)[i] = make_uint2(lo, hi);
}

// ---------------- fp32 in[R][C] -> bf16 out[C][R] (LDS tiled transpose) ----
__global__ __launch_bounds__(256) void k_trcvt(const float* __restrict__ in,
                                               u16* __restrict__ out, int R, int C) {
  __shared__ float tile[64][65];
  const int tid = threadIdx.x;
  const int r0 = blockIdx.y * 64, c0 = blockIdx.x * 64;
  const int tr = tid >> 4;
  const int tc4 = (tid & 15) * 4;
#pragma unroll
  for (int i = 0; i < 4; ++i) {
    const float4 v = *reinterpret_cast<const float4*>(
        &in[(size_t)(r0 + i * 16 + tr) * C + c0 + tc4]);
    tile[i * 16 + tr][tc4 + 0] = v.x;
    tile[i * 16 + tr][tc4 + 1] = v.y;
    tile[i * 16 + tr][tc4 + 2] = v.z;
    tile[i * 16 + tr][tc4 + 3] = v.w;
  }
  __syncthreads();
#pragma unroll
  for (int i = 0; i < 4; ++i) {
    const int c = i * 16 + tr;
    const int r4 = tc4;
    u32 lo = (u32)f2b(tile[r4 + 0][c]) | ((u32)f2b(tile[r4 + 1][c]) << 16);
    u32 hi = (u32)f2b(tile[r4 + 2][c]) | ((u32)f2b(tile[r4 + 3][c]) << 16);
    *reinterpret_cast<uint2*>(&out[(size_t)(c0 + c) * R + r0 + r4]) =
        make_uint2(lo, hi);
  }
}

// ---------------- bf16 GEMM, m97 structure: C = A @ Bt^T ----------------
// A: [M][K] bf16 row-major. Bt: [N][K] bf16 row-major (B transposed).
// 128x128 tile, BK=32, 4 waves (2x2), each wave 64x64 = 4x4 MFMA frags.
template <int F32OUT>
__global__ __launch_bounds__(256) void k_gemm(const u16* __restrict__ A,
                                              const u16* __restrict__ Bt,
                                              void* __restrict__ Cout,
                                              int M, int N, int K) {
  __shared__ u16 As[128 * 32];
  __shared__ u16 Bs[128 * 32];
  const int tid = threadIdx.x;
  const int lane = tid & 63;
  const int w = tid >> 6;
  const int wm = w >> 1, wn = w & 1;
  const int l15 = lane & 15, lg = lane >> 4;
  const int brow = blockIdx.y * 128;
  const int bcol = blockIdx.x * 128;

  f32x4 acc[4][4] = {};

  const int r0 = tid >> 2;          // row within 64-row half, per staging pass
  const int k8 = (tid & 3) * 8;     // k-offset of this thread's 16B chunk
  const u16* Ag0 = A + (size_t)(brow + r0) * K + k8;
  const u16* Ag1 = A + (size_t)(brow + 64 + r0) * K + k8;
  const u16* Bg0 = Bt + (size_t)(bcol + r0) * K + k8;
  const u16* Bg1 = Bt + (size_t)(bcol + 64 + r0) * K + k8;
  u16* Asl0 = As + tid * 8;
  u16* Asl1 = As + 2048 + tid * 8;
  u16* Bsl0 = Bs + tid * 8;
  u16* Bsl1 = Bs + 2048 + tid * 8;

  for (int k0 = 0; k0 < K; k0 += 32) {
    gll16(Ag0 + k0, Asl0);
    gll16(Ag1 + k0, Asl1);
    gll16(Bg0 + k0, Bsl0);
    gll16(Bg1 + k0, Bsl1);
    __syncthreads();
    bf16x8 a[4], b[4];
#pragma unroll
    for (int m = 0; m < 4; ++m)
      a[m] = *(const bf16x8*)&As[(wm * 64 + m * 16 + l15) * 32 + lg * 8];
#pragma unroll
    for (int n = 0; n < 4; ++n)
      b[n] = *(const bf16x8*)&Bs[(wn * 64 + n * 16 + l15) * 32 + lg * 8];
#pragma unroll
    for (int m = 0; m < 4; ++m)
#pragma unroll
      for (int n = 0; n < 4; ++n)
        acc[m][n] = MFMA(a[m], b[n], acc[m][n]);
    __syncthreads();
  }

#pragma unroll
  for (int m = 0; m < 4; ++m) {
    const int row = brow + wm * 64 + m * 16 + lg * 4;
#pragma unroll
    for (int n = 0; n < 4; ++n) {
      const int col = bcol + wn * 64 + n * 16 + l15;
#pragma unroll
      for (int r = 0; r < 4; ++r) {
        const float v = acc[m][n][r];
        if (F32OUT)
          ((float*)Cout)[(size_t)(row + r) * N + col] = v;
        else
          ((u16*)Cout)[(size_t)(row + r) * N + col] = f2b(v);
      }
    }
  }
}

// ---------------- fused causal flash attention ----------------
// qkv: [4096][3072] bf16 (per batch rows 2048). y: [4096][1024] bf16.
// Block: 256 thr (4 waves), 128 q-rows (32/wave), KV tile = 64.
__global__ __launch_bounds__(256) void k_attn(const u16* __restrict__ qkv,
                                              u16* __restrict__ y) {
  __shared__ u16 Kl[64 * 64];      // [kk][d], XOR-swizzled
  __shared__ u16 Vt[64 * 64];      // [d][t], XOR-swizzled
  __shared__ u16 Pl[4][32 * 64];   // per-wave [q][kk], XOR-swizzled
  const int tid = threadIdx.x;
  const int lane = tid & 63;
  const int w = tid >> 6;
  const int l15 = lane & 15, lg = lane >> 4;
  const int bh = blockIdx.y;
  const int b = bh >> 4, h = bh & 15;
  const int qb = blockIdx.x * 128;
  const int qw0 = qb + w * 32;

  // Q fragments in registers (32 rows x 64 d per wave)
  bf16x8 aq[2][2];
#pragma unroll
  for (int m = 0; m < 2; ++m)
#pragma unroll
    for (int kd = 0; kd < 2; ++kd)
      aq[m][kd] = *(const bf16x8*)&qkv[(size_t)(b * 2048 + qw0 + m * 16 + l15) * 3072 +
                                       h * 64 + kd * 32 + lg * 8];

  f32x4 acc[2][4] = {};
  float mrun[2][4], lrun[2][4];
#pragma unroll
  for (int m = 0; m < 2; ++m)
#pragma unroll
    for (int r = 0; r < 4; ++r) { mrun[m][r] = -1e30f; lrun[m][r] = 0.f; }

  const u16* Kg = qkv + (size_t)(b * 2048) * 3072 + 1024 + h * 64;
  const u16* Vg = qkv + (size_t)(b * 2048) * 3072 + 2048 + h * 64;

  for (int t0 = 0; t0 < qb + 128; t0 += 64) {
    // stage K tile [64][64] via global_load_lds with pre-swizzled source
#pragma unroll
    for (int p = 0; p < 2; ++p) {
      const int slot = p * 256 + tid;
      const int row = slot >> 3;
      const int col = (((slot * 16) & 127) ^ ((row & 7) << 4)) >> 1;
      gll16(Kg + (size_t)(t0 + row) * 3072 + col, (u16*)Kl + slot * 8);
    }
    // stage V^T tile [d][t] via register round-trip, swizzled writes
#pragma unroll
    for (int p = 0; p < 2; ++p) {
      const int t = p * 32 + (tid >> 3);
      const int d8 = (tid & 7) * 8;
      bf16x8 v = *(const bf16x8*)&Vg[(size_t)(t0 + t) * 3072 + d8];
#pragma unroll
      for (int j = 0; j < 8; ++j) {
        const int d = d8 + j;
        const int ba = ((d * 128 + t * 2) ^ ((d & 7) << 4));
        ((u16*)Vt)[ba >> 1] = (u16)v[j];
      }
    }
    __syncthreads();

    if (t0 <= qw0 + 31) {
      // ---- S = Q K^T ----
      bf16x8 bk[4][2];
#pragma unroll
      for (int n = 0; n < 4; ++n)
#pragma unroll
        for (int kd = 0; kd < 2; ++kd) {
          const int row = n * 16 + l15;
          const int ba = (row * 128 + (kd * 32 + lg * 8) * 2) ^ ((row & 7) << 4);
          bk[n][kd] = *(const bf16x8*)((const char*)Kl + ba);
        }
      f32x4 s[2][4];
#pragma unroll
      for (int m = 0; m < 2; ++m)
#pragma unroll
        for (int n = 0; n < 4; ++n) {
          f32x4 z = {};
          z = MFMA(aq[m][0], bk[n][0], z);
          z = MFMA(aq[m][1], bk[n][1], z);
          s[m][n] = z;
        }
      // ---- online softmax (rows lane-parallel over 16-groups) ----
#pragma unroll
      for (int m = 0; m < 2; ++m) {
#pragma unroll
        for (int r = 0; r < 4; ++r) {
          const int qrow = qw0 + m * 16 + lg * 4 + r;
          float smax = -1e30f;
#pragma unroll
          for (int n = 0; n < 4; ++n) {
            const int kk = t0 + n * 16 + l15;
            float v = s[m][n][r] * 0.125f;
            v = (kk > qrow) ? -1e30f : v;
            s[m][n][r] = v;
            smax = fmaxf(smax, v);
          }
#pragma unroll
          for (int off = 1; off < 16; off <<= 1)
            smax = fmaxf(smax, __shfl_xor(smax, off));
          const float mold = mrun[m][r];
          const float mnew = fmaxf(mold, smax);
          const float scale = __expf(mold - mnew);
          float rsum = 0.f;
#pragma unroll
          for (int n = 0; n < 4; ++n) {
            float p = __expf(s[m][n][r] - mnew);
            p = (s[m][n][r] <= -1e29f) ? 0.f : p;
            s[m][n][r] = p;
            rsum += p;
          }
#pragma unroll
          for (int off = 1; off < 16; off <<= 1)
            rsum += __shfl_xor(rsum, off);
          mrun[m][r] = mnew;
          lrun[m][r] = lrun[m][r] * scale + rsum;
#pragma unroll
          for (int n = 0; n < 4; ++n)
            acc[m][n][r] *= scale;
        }
      }
      // ---- write P to per-wave LDS (swizzled) ----
#pragma unroll
      for (int m = 0; m < 2; ++m)
#pragma unroll
        for (int n = 0; n < 4; ++n)
#pragma unroll
          for (int r = 0; r < 4; ++r) {
            const int q = m * 16 + lg * 4 + r;
            const int kk = n * 16 + l15;
            const int ba = (q * 128 + kk * 2) ^ ((q & 7) << 4);
            ((u16*)Pl[w])[ba >> 1] = f2b(s[m][n][r]);
          }
      // ---- O += P V ----
      bf16x8 pa[2][2], vb[4][2];
#pragma unroll
      for (int m = 0; m < 2; ++m)
#pragma unroll
        for (int kg = 0; kg < 2; ++kg) {
          const int q = m * 16 + l15;
          const int ba = (q * 128 + (kg * 32 + lg * 8) * 2) ^ ((q & 7) << 4);
          pa[m][kg] = *(const bf16x8*)((const char*)Pl[w] + ba);
        }
#pragma unroll
      for (int n = 0; n < 4; ++n)
#pragma unroll
        for (int kg = 0; kg < 2; ++kg) {
          const int d = n * 16 + l15;
          const int ba = (d * 128 + (kg * 32 + lg * 8) * 2) ^ ((d & 7) << 4);
          vb[n][kg] = *(const bf16x8*)((const char*)Vt + ba);
        }
#pragma unroll
      for (int m = 0; m < 2; ++m)
#pragma unroll
        for (int n = 0; n < 4; ++n) {
          acc[m][n] = MFMA(pa[m][0], vb[n][0], acc[m][n]);
          acc[m][n] = MFMA(pa[m][1], vb[n][1], acc[m][n]);
        }
    }
    __syncthreads();
  }

  // ---- epilogue: normalize and store y (bf16) ----
#pragma unroll
  for (int m = 0; m < 2; ++m)
#pragma unroll
    for (int r = 0; r < 4; ++r) {
      const int q = qw0 + m * 16 + lg * 4 + r;
      const float inv = 1.0f / lrun[m][r];
#pragma unroll
      for (int n = 0; n < 4; ++n) {
        const int col = h * 64 + n * 16 + l15;
        y[(size_t)(b * 2048 + q) * 1024 + col] = f2b(acc[m][n][r] * inv);
      }
    }
}

// ---------------- host launch ----------------
extern "C" void kernel_launch(void* const* d_in, const int* in_sizes, int n_in,
                              void* d_out, int out_size, void* d_ws, size_t ws_size,
                              hipStream_t stream) {
  const float* x  = (const float*)d_in[0];   // [2,2048,1024]
  const float* wa = (const float*)d_in[1];   // [1024,3072]
  const float* wp = (const float*)d_in[2];   // [1024,1024]
  float* out = (float*)d_out;                // [2,2048,1024] fp32

  u16* xb  = (u16*)d_ws;                 // [4096][1024] bf16
  u16* wat = xb + (size_t)4096 * 1024;   // [3072][1024] bf16 (w_attn^T)
  u16* wpt = wat + (size_t)3072 * 1024;  // [1024][1024] bf16 (w_proj^T)
  u16* qkv = wpt + (size_t)1024 * 1024;  // [4096][3072] bf16
  u16* yb  = qkv + (size_t)4096 * 3072;  // [4096][1024] bf16

  // convert inputs to bf16 (weights transposed to B^T layout)
  k_cvt<<<4096, 256, 0, stream>>>(x, xb, 4096 * 1024 / 4);
  k_trcvt<<<dim3(3072 / 64, 1024 / 64), 256, 0, stream>>>(wa, wat, 1024, 3072);
  k_trcvt<<<dim3(1024 / 64, 1024 / 64), 256, 0, stream>>>(wp, wpt, 1024, 1024);

  // qkv = x @ w_attn   (bf16 out)
  k_gemm<0><<<dim3(3072 / 128, 4096 / 128), 256, 0, stream>>>(xb, wat, qkv, 4096, 3072, 1024);

  // fused causal attention -> y [4096][1024] bf16
  k_attn<<<dim3(2048 / 128, 32), 256, 0, stream>>>(qkv, yb);

  // out = y @ w_proj   (fp32 out)
  k_gemm<1><<<dim3(1024 / 128, 4096 / 128), 256, 0, stream>>>(yb, wpt, out, 4096, 1024, 1024);
}

// Round 2
// 180.634 us; speedup vs baseline: 1.3507x; 1.3507x over previous
//
#include <hip/hip_runtime.h>
#include <hip/hip_bf16.h>
#include <stdint.h>

typedef unsigned short u16;
typedef unsigned int u32;
typedef float f32x4 __attribute__((ext_vector_type(4)));
typedef short bf16x8 __attribute__((ext_vector_type(8)));

#define MFMA(a, b, c) __builtin_amdgcn_mfma_f32_16x16x32_bf16((a), (b), (c), 0, 0, 0)

__device__ __forceinline__ void gll16(const void* g, void* lds) {
  __builtin_amdgcn_global_load_lds(
      (const __attribute__((address_space(1))) u32*)(uintptr_t)g,
      (__attribute__((address_space(3))) u32*)(uintptr_t)lds, 16, 0, 0);
}

__device__ __forceinline__ u16 f2b(float f) {
  union { __hip_bfloat16 h; u16 u; } cv;
  cv.h = __float2bfloat16(f);
  return cv.u;
}

// swizzle: varies across both low and mid row bits so that both the
// transpose-write instruction (uniform row&7) and the column-slice read
// (uniform row>>3 per half) see 8 distinct 16B slots -> ~2-way (free).
__device__ __forceinline__ int sw(int r) { return ((r ^ (r >> 3)) & 7) << 4; }

// ---------------- fp32 -> bf16 elementwise (vectorized) ----------------
__global__ __launch_bounds__(256) void k_cvt(const float* __restrict__ in,
                                             u16* __restrict__ out, int n4) {
  int i = blockIdx.x * 256 + threadIdx.x;
  if (i >= n4) return;
  const float4 v = reinterpret_cast<const float4*>(in)[i];
  u32 lo = (u32)f2b(v.x) | ((u32)f2b(v.y) << 16);
  u32 hi = (u32)f2b(v.z) | ((u32)f2b(v.w) << 16);
  reinterpret_cast<uint2*>(out)[i] = make_uint2(lo, hi);
}

// ---------------- fp32 in[R][C] -> bf16 out[C][R] (LDS tiled transpose) ----
__global__ __launch_bounds__(256) void k_trcvt(const float* __restrict__ in,
                                               u16* __restrict__ out, int R, int C) {
  __shared__ float tile[64][65];
  const int tid = threadIdx.x;
  const int r0 = blockIdx.y * 64, c0 = blockIdx.x * 64;
  const int tr = tid >> 4;
  const int tc4 = (tid & 15) * 4;
#pragma unroll
  for (int i = 0; i < 4; ++i) {
    const float4 v = *reinterpret_cast<const float4*>(
        &in[(size_t)(r0 + i * 16 + tr) * C + c0 + tc4]);
    tile[i * 16 + tr][tc4 + 0] = v.x;
    tile[i * 16 + tr][tc4 + 1] = v.y;
    tile[i * 16 + tr][tc4 + 2] = v.z;
    tile[i * 16 + tr][tc4 + 3] = v.w;
  }
  __syncthreads();
#pragma unroll
  for (int i = 0; i < 4; ++i) {
    const int c = i * 16 + tr;
    const int r4 = tc4;
    u32 lo = (u32)f2b(tile[r4 + 0][c]) | ((u32)f2b(tile[r4 + 1][c]) << 16);
    u32 hi = (u32)f2b(tile[r4 + 2][c]) | ((u32)f2b(tile[r4 + 3][c]) << 16);
    *reinterpret_cast<uint2*>(&out[(size_t)(c0 + c) * R + r0 + r4]) =
        make_uint2(lo, hi);
  }
}

// ---------------- bf16 GEMM, m97 structure: C = A @ Bt^T ----------------
template <int F32OUT>
__global__ __launch_bounds__(256) void k_gemm(const u16* __restrict__ A,
                                              const u16* __restrict__ Bt,
                                              void* __restrict__ Cout,
                                              int M, int N, int K) {
  __shared__ u16 As[128 * 32];
  __shared__ u16 Bs[128 * 32];
  const int tid = threadIdx.x;
  const int lane = tid & 63;
  const int w = tid >> 6;
  const int wm = w >> 1, wn = w & 1;
  const int l15 = lane & 15, lg = lane >> 4;
  const int brow = blockIdx.y * 128;
  const int bcol = blockIdx.x * 128;

  f32x4 acc[4][4] = {};

  const int r0 = tid >> 2;
  const int k8 = (tid & 3) * 8;
  const u16* Ag0 = A + (size_t)(brow + r0) * K + k8;
  const u16* Ag1 = A + (size_t)(brow + 64 + r0) * K + k8;
  const u16* Bg0 = Bt + (size_t)(bcol + r0) * K + k8;
  const u16* Bg1 = Bt + (size_t)(bcol + 64 + r0) * K + k8;
  u16* Asl0 = As + tid * 8;
  u16* Asl1 = As + 2048 + tid * 8;
  u16* Bsl0 = Bs + tid * 8;
  u16* Bsl1 = Bs + 2048 + tid * 8;

  for (int k0 = 0; k0 < K; k0 += 32) {
    gll16(Ag0 + k0, Asl0);
    gll16(Ag1 + k0, Asl1);
    gll16(Bg0 + k0, Bsl0);
    gll16(Bg1 + k0, Bsl1);
    __syncthreads();
    bf16x8 a[4], b[4];
#pragma unroll
    for (int m = 0; m < 4; ++m)
      a[m] = *(const bf16x8*)&As[(wm * 64 + m * 16 + l15) * 32 + lg * 8];
#pragma unroll
    for (int n = 0; n < 4; ++n)
      b[n] = *(const bf16x8*)&Bs[(wn * 64 + n * 16 + l15) * 32 + lg * 8];
#pragma unroll
    for (int m = 0; m < 4; ++m)
#pragma unroll
      for (int n = 0; n < 4; ++n)
        acc[m][n] = MFMA(a[m], b[n], acc[m][n]);
    __syncthreads();
  }

#pragma unroll
  for (int m = 0; m < 4; ++m) {
    const int row = brow + wm * 64 + m * 16 + lg * 4;
#pragma unroll
    for (int n = 0; n < 4; ++n) {
      const int col = bcol + wn * 64 + n * 16 + l15;
#pragma unroll
      for (int r = 0; r < 4; ++r) {
        const float v = acc[m][n][r];
        if (F32OUT)
          ((float*)Cout)[(size_t)(row + r) * N + col] = v;
        else
          ((u16*)Cout)[(size_t)(row + r) * N + col] = f2b(v);
      }
    }
  }
}

// ---------------- fused causal flash attention (v2: pipelined) ----------
// qkv: [4096][3072] bf16. y: [4096][1024] bf16.
// 256 thr / 4 waves; 128 q-rows per block (32/wave); KV tile = 64.
// Double-buffered K,V^T LDS; swapped QK^T (S^T) for in-lane softmax rows;
// single barrier per tile; LPT + XCD-chunked block mapping.
__global__ __launch_bounds__(256) void k_attn(const u16* __restrict__ qkv,
                                              u16* __restrict__ y) {
  __shared__ u16 Kl[2][64 * 64];   // [t][d], swizzled sw(t)
  __shared__ u16 Vt[2][64 * 64];   // [d][t], swizzled sw(d)
  __shared__ u16 Pl[4][32 * 64];   // per-wave [q][t], swizzled sw(q)
  const int tid = threadIdx.x;
  const int lane = tid & 63;
  const int w = tid >> 6;
  const int l15 = lane & 15, lg = lane >> 4;

  // block mapping: 8 XCDs x (4 heads x 16 q-tiles). Heavy q-tiles first (LPT);
  // per-XCD working set = one head's K/V (~512KB) -> L2-resident.
  const int lin = blockIdx.x;
  const int xcd = lin & 7;
  const int idx = lin >> 3;
  const int bh = xcd * 4 + (idx >> 4);
  const int qi = 15 - (idx & 15);
  const int b = bh >> 4, h = bh & 15;
  const int qb = qi * 128;
  const int qw0 = qb + w * 32;

  const u16* Qg = qkv + (size_t)(b * 2048) * 3072 + h * 64;
  const u16* Kg = qkv + (size_t)(b * 2048) * 3072 + 1024 + h * 64;
  const u16* Vg = qkv + (size_t)(b * 2048) * 3072 + 2048 + h * 64;

  // Q fragments (32 q-rows x 64 d per wave)
  bf16x8 aq[2][2];
#pragma unroll
  for (int m = 0; m < 2; ++m)
#pragma unroll
    for (int kd = 0; kd < 2; ++kd)
      aq[m][kd] = *(const bf16x8*)&Qg[(size_t)(qw0 + m * 16 + l15) * 3072 +
                                      kd * 32 + lg * 8];

  f32x4 acc[2][4] = {};
  float mrun[2] = {-1e30f, -1e30f};
  float lrun[2] = {0.f, 0.f};

  const int t2 = tid >> 3;          // 0..31: owns t-pair (2*t2, 2*t2+1)
  const int d8 = (tid & 7) * 8;     // 8 d-values per thread

  const int ntile = (qb + 128) >> 6;

  // --- prologue: stage tile 0 into buffer 0 ---
  {
#pragma unroll
    for (int p = 0; p < 2; ++p) {
      const int slot = p * 256 + tid;
      const int row = slot >> 3;
      const int colb = (slot & 7) * 16;
      gll16(Kg + (size_t)row * 3072 + ((colb ^ sw(row)) >> 1),
            (u16*)Kl[0] + slot * 8);
    }
    const bf16x8 v0 = *(const bf16x8*)&Vg[(size_t)(2 * t2) * 3072 + d8];
    const bf16x8 v1 = *(const bf16x8*)&Vg[(size_t)(2 * t2 + 1) * 3072 + d8];
#pragma unroll
    for (int j = 0; j < 8; ++j) {
      const int d = d8 + j;
      const u32 val = (u32)(u16)v0[j] | ((u32)(u16)v1[j] << 16);
      *(u32*)((char*)Vt[0] + ((d * 128 + t2 * 4) ^ sw(d))) = val;
    }
  }
  __syncthreads();

  int cur = 0;
  for (int it = 0; it < ntile; ++it) {
    const int t0 = it * 64;
    const bool more = (it + 1 < ntile);
    bf16x8 v0, v1;
    if (more) {
      const int tn = t0 + 64;
#pragma unroll
      for (int p = 0; p < 2; ++p) {
        const int slot = p * 256 + tid;
        const int row = slot >> 3;
        const int colb = (slot & 7) * 16;
        gll16(Kg + (size_t)(tn + row) * 3072 + ((colb ^ sw(row)) >> 1),
              (u16*)Kl[cur ^ 1] + slot * 8);
      }
      v0 = *(const bf16x8*)&Vg[(size_t)(tn + 2 * t2) * 3072 + d8];
      v1 = *(const bf16x8*)&Vg[(size_t)(tn + 2 * t2 + 1) * 3072 + d8];
    }

    if (t0 <= qw0 + 31) {
      // ---- S^T = K Q^T : lane holds kk = n*16+lg*4+r, q = m*16+l15 ----
      bf16x8 bk[4][2];
#pragma unroll
      for (int n = 0; n < 4; ++n)
#pragma unroll
        for (int kd = 0; kd < 2; ++kd) {
          const int row = n * 16 + l15;
          bk[n][kd] = *(const bf16x8*)((const char*)Kl[cur] +
                          ((row * 128 + kd * 64 + lg * 16) ^ sw(row)));
        }
      f32x4 st[4][2];
#pragma unroll
      for (int n = 0; n < 4; ++n)
#pragma unroll
        for (int m = 0; m < 2; ++m) {
          f32x4 z = {};
          z = MFMA(bk[n][0], aq[m][0], z);
          z = MFMA(bk[n][1], aq[m][1], z);
          st[n][m] = z;
        }

      const bool needmask = (t0 + 63 > qw0);
      float scale2[2];
#pragma unroll
      for (int m = 0; m < 2; ++m) {
        const int qrow = qw0 + m * 16 + l15;
        float zz[4][4];
        float mx = -1e30f;
#pragma unroll
        for (int n = 0; n < 4; ++n)
#pragma unroll
          for (int r = 0; r < 4; ++r) {
            // 1/sqrt(64) * log2(e): softmax in exp2 domain
            float v = st[n][m][r] * 0.18033688011112042f;
            if (needmask) {
              const int kkg = t0 + n * 16 + lg * 4 + r;
              v = (kkg > qrow) ? -1e30f : v;
            }
            zz[n][r] = v;
            mx = fmaxf(mx, v);
          }
        mx = fmaxf(mx, __shfl_xor(mx, 16));
        mx = fmaxf(mx, __shfl_xor(mx, 32));
        const float mo = mrun[m];
        const float mn = fmaxf(mo, mx);
        const float sc = exp2f(mo - mn);
        float rs = 0.f;
#pragma unroll
        for (int n = 0; n < 4; ++n)
#pragma unroll
          for (int r = 0; r < 4; ++r) {
            const float p = exp2f(zz[n][r] - mn);
            zz[n][r] = p;
            rs += p;
          }
        rs += __shfl_xor(rs, 16);
        rs += __shfl_xor(rs, 32);
        mrun[m] = mn;
        lrun[m] = lrun[m] * sc + rs;
        scale2[m] = sc;
        // write P packed as u32 (kk pairs are in-lane with S^T layout)
        const int q = m * 16 + l15;
#pragma unroll
        for (int n = 0; n < 4; ++n)
#pragma unroll
          for (int pr = 0; pr < 2; ++pr) {
            const u32 val = (u32)f2b(zz[n][2 * pr]) |
                            ((u32)f2b(zz[n][2 * pr + 1]) << 16);
            *(u32*)((char*)Pl[w] +
                    ((q * 128 + n * 32 + lg * 8 + pr * 4) ^ sw(q))) = val;
          }
      }

      // ---- rescale O by exp2(mold-mnew), broadcast to acc row owners ----
#pragma unroll
      for (int m = 0; m < 2; ++m)
#pragma unroll
        for (int r = 0; r < 4; ++r) {
          const float sc = __shfl(scale2[m], lg * 4 + r);
#pragma unroll
          for (int n = 0; n < 4; ++n) acc[m][n][r] *= sc;
        }

      // ---- O += P V ----
      bf16x8 pa[2][2];
#pragma unroll
      for (int m = 0; m < 2; ++m)
#pragma unroll
        for (int kg = 0; kg < 2; ++kg) {
          const int q = m * 16 + l15;
          pa[m][kg] = *(const bf16x8*)((const char*)Pl[w] +
                          ((q * 128 + kg * 64 + lg * 16) ^ sw(q)));
        }
      bf16x8 vb[4][2];
#pragma unroll
      for (int n = 0; n < 4; ++n)
#pragma unroll
        for (int kg = 0; kg < 2; ++kg) {
          const int d = n * 16 + l15;
          vb[n][kg] = *(const bf16x8*)((const char*)Vt[cur] +
                          ((d * 128 + kg * 64 + lg * 16) ^ sw(d)));
        }
#pragma unroll
      for (int m = 0; m < 2; ++m)
#pragma unroll
        for (int n = 0; n < 4; ++n) {
          acc[m][n] = MFMA(pa[m][0], vb[n][0], acc[m][n]);
          acc[m][n] = MFMA(pa[m][1], vb[n][1], acc[m][n]);
        }
    }

    // late half of the V^T async stage (T14): write regs -> LDS buf^1
    if (more) {
#pragma unroll
      for (int j = 0; j < 8; ++j) {
        const int d = d8 + j;
        const u32 val = (u32)(u16)v0[j] | ((u32)(u16)v1[j] << 16);
        *(u32*)((char*)Vt[cur ^ 1] + ((d * 128 + t2 * 4) ^ sw(d))) = val;
      }
    }
    __syncthreads();
    cur ^= 1;
  }

  // ---- epilogue: normalize and store y (bf16) ----
#pragma unroll
  for (int m = 0; m < 2; ++m)
#pragma unroll
    for (int r = 0; r < 4; ++r) {
      const int q = qw0 + m * 16 + lg * 4 + r;
      const float linv = 1.0f / __shfl(lrun[m], lg * 4 + r);
#pragma unroll
      for (int n = 0; n < 4; ++n)
        y[(size_t)(b * 2048 + q) * 1024 + h * 64 + n * 16 + l15] =
            f2b(acc[m][n][r] * linv);
    }
}

// ---------------- host launch ----------------
extern "C" void kernel_launch(void* const* d_in, const int* in_sizes, int n_in,
                              void* d_out, int out_size, void* d_ws, size_t ws_size,
                              hipStream_t stream) {
  const float* x  = (const float*)d_in[0];   // [2,2048,1024]
  const float* wa = (const float*)d_in[1];   // [1024,3072]
  const float* wp = (const float*)d_in[2];   // [1024,1024]
  float* out = (float*)d_out;                // [2,2048,1024] fp32

  u16* xb  = (u16*)d_ws;                 // [4096][1024] bf16
  u16* wat = xb + (size_t)4096 * 1024;   // [3072][1024] bf16 (w_attn^T)
  u16* wpt = wat + (size_t)3072 * 1024;  // [1024][1024] bf16 (w_proj^T)
  u16* qkv = wpt + (size_t)1024 * 1024;  // [4096][3072] bf16
  u16* yb  = qkv + (size_t)4096 * 3072;  // [4096][1024] bf16

  k_cvt<<<4096, 256, 0, stream>>>(x, xb, 4096 * 1024 / 4);
  k_trcvt<<<dim3(3072 / 64, 1024 / 64), 256, 0, stream>>>(wa, wat, 1024, 3072);
  k_trcvt<<<dim3(1024 / 64, 1024 / 64), 256, 0, stream>>>(wp, wpt, 1024, 1024);

  // qkv = x @ w_attn   (bf16 out)
  k_gemm<0><<<dim3(3072 / 128, 4096 / 128), 256, 0, stream>>>(xb, wat, qkv, 4096, 3072, 1024);

  // fused causal attention -> y [4096][1024] bf16
  k_attn<<<512, 256, 0, stream>>>(qkv, yb);

  // out = y @ w_proj   (fp32 out)
  k_gemm<1><<<dim3(1024 / 128, 4096 / 128), 256, 0, stream>>>(yb, wpt, out, 4096, 1024, 1024);
}

// Round 3
// 140.592 us; speedup vs baseline: 1.7354x; 1.2848x over previous
//
#include <hip/hip_runtime.h>
#include <hip/hip_bf16.h>
#include <stdint.h>

typedef unsigned short u16;
typedef unsigned int u32;
typedef unsigned long long u64;
typedef float f32x4 __attribute__((ext_vector_type(4)));
typedef short bf16x8 __attribute__((ext_vector_type(8)));

#define MFMA(a, b, c) __builtin_amdgcn_mfma_f32_16x16x32_bf16((a), (b), (c), 0, 0, 0)

__device__ __forceinline__ void gll16(const void* g, void* lds) {
  __builtin_amdgcn_global_load_lds(
      (const __attribute__((address_space(1))) u32*)(uintptr_t)g,
      (__attribute__((address_space(3))) u32*)(uintptr_t)lds, 16, 0, 0);
}

__device__ __forceinline__ u16 f2b(float f) {
  union { __hip_bfloat16 h; u16 u; } cv;
  cv.h = __float2bfloat16(f);
  return cv.u;
}
__device__ __forceinline__ float b2f(u16 b) {
  union { u32 u; float f; } cv;
  cv.u = (u32)b << 16;
  return cv.f;
}

// swizzle: conflict-free for both transpose-writes and column-slice reads
__device__ __forceinline__ int sw(int r) { return ((r ^ (r >> 3)) & 7) << 4; }

// ---------------- fp32 -> bf16 elementwise (vectorized) ----------------
__global__ __launch_bounds__(256) void k_cvt(const float* __restrict__ in,
                                             u16* __restrict__ out, int n4) {
  int i = blockIdx.x * 256 + threadIdx.x;
  if (i >= n4) return;
  const float4 v = reinterpret_cast<const float4*>(in)[i];
  u32 lo = (u32)f2b(v.x) | ((u32)f2b(v.y) << 16);
  u32 hi = (u32)f2b(v.z) | ((u32)f2b(v.w) << 16);
  reinterpret_cast<uint2*>(out)[i] = make_uint2(lo, hi);
}

// ---------------- fp32 in[R][C] -> bf16 out[C][R] (LDS tiled transpose) ----
__global__ __launch_bounds__(256) void k_trcvt(const float* __restrict__ in,
                                               u16* __restrict__ out, int R, int C) {
  __shared__ float tile[64][65];
  const int tid = threadIdx.x;
  const int r0 = blockIdx.y * 64, c0 = blockIdx.x * 64;
  const int tr = tid >> 4;
  const int tc4 = (tid & 15) * 4;
#pragma unroll
  for (int i = 0; i < 4; ++i) {
    const float4 v = *reinterpret_cast<const float4*>(
        &in[(size_t)(r0 + i * 16 + tr) * C + c0 + tc4]);
    tile[i * 16 + tr][tc4 + 0] = v.x;
    tile[i * 16 + tr][tc4 + 1] = v.y;
    tile[i * 16 + tr][tc4 + 2] = v.z;
    tile[i * 16 + tr][tc4 + 3] = v.w;
  }
  __syncthreads();
#pragma unroll
  for (int i = 0; i < 4; ++i) {
    const int c = i * 16 + tr;
    const int r4 = tc4;
    u32 lo = (u32)f2b(tile[r4 + 0][c]) | ((u32)f2b(tile[r4 + 1][c]) << 16);
    u32 hi = (u32)f2b(tile[r4 + 2][c]) | ((u32)f2b(tile[r4 + 3][c]) << 16);
    *reinterpret_cast<uint2*>(&out[(size_t)(c0 + c) * R + r0 + r4]) =
        make_uint2(lo, hi);
  }
}

// ---------------- bf16 GEMM, m97 structure: C = A @ Bt^T ----------------
template <int F32OUT>
__global__ __launch_bounds__(256) void k_gemm(const u16* __restrict__ A,
                                              const u16* __restrict__ Bt,
                                              void* __restrict__ Cout,
                                              int M, int N, int K) {
  __shared__ u16 As[128 * 32];
  __shared__ u16 Bs[128 * 32];
  const int tid = threadIdx.x;
  const int lane = tid & 63;
  const int w = tid >> 6;
  const int wm = w >> 1, wn = w & 1;
  const int l15 = lane & 15, lg = lane >> 4;
  const int brow = blockIdx.y * 128;
  const int bcol = blockIdx.x * 128;

  f32x4 acc[4][4] = {};

  const int r0 = tid >> 2;
  const int k8 = (tid & 3) * 8;
  const u16* Ag0 = A + (size_t)(brow + r0) * K + k8;
  const u16* Ag1 = A + (size_t)(brow + 64 + r0) * K + k8;
  const u16* Bg0 = Bt + (size_t)(bcol + r0) * K + k8;
  const u16* Bg1 = Bt + (size_t)(bcol + 64 + r0) * K + k8;
  u16* Asl0 = As + tid * 8;
  u16* Asl1 = As + 2048 + tid * 8;
  u16* Bsl0 = Bs + tid * 8;
  u16* Bsl1 = Bs + 2048 + tid * 8;

  for (int k0 = 0; k0 < K; k0 += 32) {
    gll16(Ag0 + k0, Asl0);
    gll16(Ag1 + k0, Asl1);
    gll16(Bg0 + k0, Bsl0);
    gll16(Bg1 + k0, Bsl1);
    __syncthreads();
    bf16x8 a[4], b[4];
#pragma unroll
    for (int m = 0; m < 4; ++m)
      a[m] = *(const bf16x8*)&As[(wm * 64 + m * 16 + l15) * 32 + lg * 8];
#pragma unroll
    for (int n = 0; n < 4; ++n)
      b[n] = *(const bf16x8*)&Bs[(wn * 64 + n * 16 + l15) * 32 + lg * 8];
#pragma unroll
    for (int m = 0; m < 4; ++m)
#pragma unroll
      for (int n = 0; n < 4; ++n)
        acc[m][n] = MFMA(a[m], b[n], acc[m][n]);
    __syncthreads();
  }

#pragma unroll
  for (int m = 0; m < 4; ++m) {
    const int row = brow + wm * 64 + m * 16 + lg * 4;
#pragma unroll
    for (int n = 0; n < 4; ++n) {
      const int col = bcol + wn * 64 + n * 16 + l15;
#pragma unroll
      for (int r = 0; r < 4; ++r) {
        const float v = acc[m][n][r];
        if (F32OUT)
          ((float*)Cout)[(size_t)(row + r) * N + col] = v;
        else
          ((u16*)Cout)[(size_t)(row + r) * N + col] = f2b(v);
      }
    }
  }
}

// ---------------- fused causal flash attention (v3) ----------------------
// 1024 blocks x 256 thr (4 waves). 64 q-rows/block (16/wave). KV tile = 64.
// Whole grid co-resident (4 blocks/CU); per-CU work balanced by mapping.
// Transposed PV (O^T) -> softmax stats lane-local (q = l15), no shuffles
// outside the 2-op cross-lg reduction. Defer-max (THR=8 in log2 domain).
__global__ __launch_bounds__(256, 4) void k_attn(const u16* __restrict__ qkv,
                                                 u16* __restrict__ y) {
  __shared__ u16 Kl[2][64 * 64];   // [t][d], swizzled sw(t)
  __shared__ u16 Vt[2][64 * 64];   // [d][t], swizzled sw(d)
  __shared__ u16 Pl[4][16 * 64];   // per-wave [q][t], swizzled sw(q)
  const int tid = threadIdx.x;
  const int lane = tid & 63;
  const int w = tid >> 6;
  const int l15 = lane & 15, lg = lane >> 4;

  // mapping: 8 XCDs x 128 blocks. Per XCD: round r (=idx>>5) is head r;
  // qi alternates ascending/descending per round so each CU's 4 resident
  // blocks sum to a constant 66 tile-steps (causal balance).
  const int lin = blockIdx.x;
  const int xcd = lin & 7;
  const int idx = lin >> 3;            // 0..127
  const int round = idx >> 5;          // 0..3
  const int c = idx & 31;
  const int qi = (round & 1) ? c : 31 - c;
  const int bh = xcd * 4 + round;
  const int b = bh >> 4, h = bh & 15;
  const int qw0 = qi * 64 + w * 16;    // wave's first q row

  const u16* Qg = qkv + (size_t)(b * 2048) * 3072 + h * 64;
  const u16* Kg = qkv + (size_t)(b * 2048) * 3072 + 1024 + h * 64;
  const u16* Vg = qkv + (size_t)(b * 2048) * 3072 + 2048 + h * 64;

  // Q b-fragments (col q = l15, k = kd*32+lg*8), pre-scaled by 1/8*log2(e)
  bf16x8 aq[2];
#pragma unroll
  for (int kd = 0; kd < 2; ++kd) {
    bf16x8 v = *(const bf16x8*)&Qg[(size_t)(qw0 + l15) * 3072 + kd * 32 + lg * 8];
#pragma unroll
    for (int j = 0; j < 8; ++j)
      v[j] = (short)f2b(b2f((u16)v[j]) * 0.18033688011112042f);
    aq[kd] = v;
  }

  f32x4 acc[4] = {};            // O^T: col q = l15, row d = n*16+lg*4+r
  float mrun = -1e30f, lrun = 0.f;

  const int t2 = tid >> 3;      // 0..31: owns t-pair (2*t2, 2*t2+1)
  const int d8 = (tid & 7) * 8; // 8 d-values per thread

  // --- prologue: stage tile 0 into buffer 0 ---
  {
#pragma unroll
    for (int p = 0; p < 2; ++p) {
      const int slot = p * 256 + tid;
      const int row = slot >> 3;
      const int colb = (slot & 7) * 16;
      gll16(Kg + (size_t)row * 3072 + ((colb ^ sw(row)) >> 1),
            (u16*)Kl[0] + slot * 8);
    }
    const bf16x8 v0 = *(const bf16x8*)&Vg[(size_t)(2 * t2) * 3072 + d8];
    const bf16x8 v1 = *(const bf16x8*)&Vg[(size_t)(2 * t2 + 1) * 3072 + d8];
#pragma unroll
    for (int j = 0; j < 8; ++j) {
      const int d = d8 + j;
      const u32 val = (u32)(u16)v0[j] | ((u32)(u16)v1[j] << 16);
      *(u32*)((char*)Vt[0] + ((d * 128 + t2 * 4) ^ sw(d))) = val;
    }
  }
  __syncthreads();

  int cur = 0;
  for (int it = 0; it <= qi; ++it) {
    const int t0 = it * 64;
    const bool more = (it < qi);
    bf16x8 v0, v1;
    if (more) {
      const int tn = t0 + 64;
#pragma unroll
      for (int p = 0; p < 2; ++p) {
        const int slot = p * 256 + tid;
        const int row = slot >> 3;
        const int colb = (slot & 7) * 16;
        gll16(Kg + (size_t)(tn + row) * 3072 + ((colb ^ sw(row)) >> 1),
              (u16*)Kl[cur ^ 1] + slot * 8);
      }
      v0 = *(const bf16x8*)&Vg[(size_t)(tn + 2 * t2) * 3072 + d8];
      v1 = *(const bf16x8*)&Vg[(size_t)(tn + 2 * t2 + 1) * 3072 + d8];
    }

    // ---- S^T = K Q^T : lane holds t = n*16+lg*4+r (row), q = l15 (col) ----
    bf16x8 bk0, bk1;
    f32x4 st[4];
#pragma unroll
    for (int n = 0; n < 4; ++n) {
      const int row = n * 16 + l15;
      bk0 = *(const bf16x8*)((const char*)Kl[cur] +
                ((row * 128 + 0 + lg * 16) ^ sw(row)));
      bk1 = *(const bf16x8*)((const char*)Kl[cur] +
                ((row * 128 + 64 + lg * 16) ^ sw(row)));
      f32x4 z = {};
      z = MFMA(bk0, aq[0], z);
      z = MFMA(bk1, aq[1], z);
      st[n] = z;
    }

    // ---- online softmax, all stats lane-local at q = l15 ----
    const int qrow = qw0 + l15;
    float mx = -1e30f;
    if (it == qi) {  // diagonal tile: causal mask
#pragma unroll
      for (int n = 0; n < 4; ++n)
#pragma unroll
        for (int r = 0; r < 4; ++r) {
          const int kkg = t0 + n * 16 + lg * 4 + r;
          float v = st[n][r];
          v = (kkg > qrow) ? -1e30f : v;
          st[n][r] = v;
          mx = fmaxf(mx, v);
        }
    } else {
#pragma unroll
      for (int n = 0; n < 4; ++n)
#pragma unroll
        for (int r = 0; r < 4; ++r) mx = fmaxf(mx, st[n][r]);
    }
    mx = fmaxf(mx, __shfl_xor(mx, 16));
    mx = fmaxf(mx, __shfl_xor(mx, 32));

    const float mo = mrun;
    const bool defer = __all(mx <= mo + 8.0f);
    const float mn = defer ? mo : fmaxf(mo, mx);
    float rs = 0.f;
#pragma unroll
    for (int n = 0; n < 4; ++n)
#pragma unroll
      for (int r = 0; r < 4; ++r) {
        const float p = exp2f(st[n][r] - mn);
        st[n][r] = p;
        rs += p;
      }
    rs += __shfl_xor(rs, 16);
    rs += __shfl_xor(rs, 32);
    if (defer) {
      lrun += rs;
    } else {
      const float sc = exp2f(mo - mn);
      lrun = lrun * sc + rs;
      mrun = mn;
#pragma unroll
      for (int n = 0; n < 4; ++n)
#pragma unroll
        for (int r = 0; r < 4; ++r) acc[n][r] *= sc;
    }

    // ---- write P[q=l15][t] packed as u64 (conflict-free b64) ----
#pragma unroll
    for (int n = 0; n < 4; ++n) {
      const u64 pk = (u64)f2b(st[n][0]) | ((u64)f2b(st[n][1]) << 16) |
                     ((u64)f2b(st[n][2]) << 32) | ((u64)f2b(st[n][3]) << 48);
      *(u64*)((char*)Pl[w] + ((l15 * 128 + n * 32 + lg * 8) ^ sw(l15))) = pk;
    }

    // ---- O^T += V^T P : A = Vt frag (row d = l15), B = P frag (col q = l15)
    bf16x8 pa0 = *(const bf16x8*)((const char*)Pl[w] +
                     ((l15 * 128 + 0 + lg * 16) ^ sw(l15)));
    bf16x8 pa1 = *(const bf16x8*)((const char*)Pl[w] +
                     ((l15 * 128 + 64 + lg * 16) ^ sw(l15)));
#pragma unroll
    for (int n = 0; n < 4; ++n) {
      const int d = n * 16 + l15;
      const bf16x8 vb0 = *(const bf16x8*)((const char*)Vt[cur] +
                             ((d * 128 + 0 + lg * 16) ^ sw(d)));
      const bf16x8 vb1 = *(const bf16x8*)((const char*)Vt[cur] +
                             ((d * 128 + 64 + lg * 16) ^ sw(d)));
      acc[n] = MFMA(vb0, pa0, acc[n]);
      acc[n] = MFMA(vb1, pa1, acc[n]);
    }

    // late half of async V stage: regs -> LDS buf^1
    if (more) {
#pragma unroll
      for (int j = 0; j < 8; ++j) {
        const int d = d8 + j;
        const u32 val = (u32)(u16)v0[j] | ((u32)(u16)v1[j] << 16);
        *(u32*)((char*)Vt[cur ^ 1] + ((d * 128 + t2 * 4) ^ sw(d))) = val;
      }
    }
    __syncthreads();
    cur ^= 1;
  }

  // ---- epilogue: normalize (lane-local l) and store y packed u64 ----
  const float linv = 1.0f / lrun;
  const size_t yrow = (size_t)(b * 2048 + qw0 + l15) * 1024 + h * 64;
#pragma unroll
  for (int n = 0; n < 4; ++n) {
    const u64 pk = (u64)f2b(acc[n][0] * linv) |
                   ((u64)f2b(acc[n][1] * linv) << 16) |
                   ((u64)f2b(acc[n][2] * linv) << 32) |
                   ((u64)f2b(acc[n][3] * linv) << 48);
    *(u64*)&y[yrow + n * 16 + lg * 4] = pk;
  }
}

// ---------------- host launch ----------------
extern "C" void kernel_launch(void* const* d_in, const int* in_sizes, int n_in,
                              void* d_out, int out_size, void* d_ws, size_t ws_size,
                              hipStream_t stream) {
  const float* x  = (const float*)d_in[0];   // [2,2048,1024]
  const float* wa = (const float*)d_in[1];   // [1024,3072]
  const float* wp = (const float*)d_in[2];   // [1024,1024]
  float* out = (float*)d_out;                // [2,2048,1024] fp32

  u16* xb  = (u16*)d_ws;                 // [4096][1024] bf16
  u16* wat = xb + (size_t)4096 * 1024;   // [3072][1024] bf16 (w_attn^T)
  u16* wpt = wat + (size_t)3072 * 1024;  // [1024][1024] bf16 (w_proj^T)
  u16* qkv = wpt + (size_t)1024 * 1024;  // [4096][3072] bf16
  u16* yb  = qkv + (size_t)4096 * 3072;  // [4096][1024] bf16

  k_cvt<<<4096, 256, 0, stream>>>(x, xb, 4096 * 1024 / 4);
  k_trcvt<<<dim3(3072 / 64, 1024 / 64), 256, 0, stream>>>(wa, wat, 1024, 3072);
  k_trcvt<<<dim3(1024 / 64, 1024 / 64), 256, 0, stream>>>(wp, wpt, 1024, 1024);

  // qkv = x @ w_attn   (bf16 out)
  k_gemm<0><<<dim3(3072 / 128, 4096 / 128), 256, 0, stream>>>(xb, wat, qkv, 4096, 3072, 1024);

  // fused causal attention -> y [4096][1024] bf16
  k_attn<<<1024, 256, 0, stream>>>(qkv, yb);

  // out = y @ w_proj   (fp32 out)
  k_gemm<1><<<dim3(1024 / 128, 4096 / 128), 256, 0, stream>>>(yb, wpt, out, 4096, 1024, 1024);
}

// Round 4
// 137.473 us; speedup vs baseline: 1.7748x; 1.0227x over previous
//
#include <hip/hip_runtime.h>
#include <hip/hip_bf16.h>
#include <stdint.h>

typedef unsigned short u16;
typedef unsigned int u32;
typedef unsigned long long u64;
typedef float f32x4 __attribute__((ext_vector_type(4)));
typedef short bf16x8 __attribute__((ext_vector_type(8)));

#define MFMA(a, b, c) __builtin_amdgcn_mfma_f32_16x16x32_bf16((a), (b), (c), 0, 0, 0)

__device__ __forceinline__ void gll16(const void* g, void* lds) {
  __builtin_amdgcn_global_load_lds(
      (const __attribute__((address_space(1))) u32*)(uintptr_t)g,
      (__attribute__((address_space(3))) u32*)(uintptr_t)lds, 16, 0, 0);
}

__device__ __forceinline__ u16 f2b(float f) {
  union { __hip_bfloat16 h; u16 u; } cv;
  cv.h = __float2bfloat16(f);
  return cv.u;
}
__device__ __forceinline__ float b2f(u16 b) {
  union { u32 u; float f; } cv;
  cv.u = (u32)b << 16;
  return cv.f;
}

// swizzle: conflict-free for both transpose-writes and column-slice reads
__device__ __forceinline__ int sw(int r) { return ((r ^ (r >> 3)) & 7) << 4; }

// ---------------- fp32 -> bf16 elementwise (vectorized) ----------------
__global__ __launch_bounds__(256) void k_cvt(const float* __restrict__ in,
                                             u16* __restrict__ out, int n4) {
  int i = blockIdx.x * 256 + threadIdx.x;
  if (i >= n4) return;
  const float4 v = reinterpret_cast<const float4*>(in)[i];
  u32 lo = (u32)f2b(v.x) | ((u32)f2b(v.y) << 16);
  u32 hi = (u32)f2b(v.z) | ((u32)f2b(v.w) << 16);
  reinterpret_cast<uint2*>(out)[i] = make_uint2(lo, hi);
}

// ---------------- fp32 in[R][C] -> bf16 out[C][R] (LDS tiled transpose) ----
__global__ __launch_bounds__(256) void k_trcvt(const float* __restrict__ in,
                                               u16* __restrict__ out, int R, int C) {
  __shared__ float tile[64][65];
  const int tid = threadIdx.x;
  const int r0 = blockIdx.y * 64, c0 = blockIdx.x * 64;
  const int tr = tid >> 4;
  const int tc4 = (tid & 15) * 4;
#pragma unroll
  for (int i = 0; i < 4; ++i) {
    const float4 v = *reinterpret_cast<const float4*>(
        &in[(size_t)(r0 + i * 16 + tr) * C + c0 + tc4]);
    tile[i * 16 + tr][tc4 + 0] = v.x;
    tile[i * 16 + tr][tc4 + 1] = v.y;
    tile[i * 16 + tr][tc4 + 2] = v.z;
    tile[i * 16 + tr][tc4 + 3] = v.w;
  }
  __syncthreads();
#pragma unroll
  for (int i = 0; i < 4; ++i) {
    const int c = i * 16 + tr;
    const int r4 = tc4;
    u32 lo = (u32)f2b(tile[r4 + 0][c]) | ((u32)f2b(tile[r4 + 1][c]) << 16);
    u32 hi = (u32)f2b(tile[r4 + 2][c]) | ((u32)f2b(tile[r4 + 3][c]) << 16);
    *reinterpret_cast<uint2*>(&out[(size_t)(c0 + c) * R + r0 + r4]) =
        make_uint2(lo, hi);
  }
}

// ---------------- bf16 GEMM, m97 structure: C = A @ Bt^T ----------------
template <int F32OUT>
__global__ __launch_bounds__(256) void k_gemm(const u16* __restrict__ A,
                                              const u16* __restrict__ Bt,
                                              void* __restrict__ Cout,
                                              int M, int N, int K) {
  __shared__ u16 As[128 * 32];
  __shared__ u16 Bs[128 * 32];
  const int tid = threadIdx.x;
  const int lane = tid & 63;
  const int w = tid >> 6;
  const int wm = w >> 1, wn = w & 1;
  const int l15 = lane & 15, lg = lane >> 4;
  const int brow = blockIdx.y * 128;
  const int bcol = blockIdx.x * 128;

  f32x4 acc[4][4] = {};

  const int r0 = tid >> 2;
  const int k8 = (tid & 3) * 8;
  const u16* Ag0 = A + (size_t)(brow + r0) * K + k8;
  const u16* Ag1 = A + (size_t)(brow + 64 + r0) * K + k8;
  const u16* Bg0 = Bt + (size_t)(bcol + r0) * K + k8;
  const u16* Bg1 = Bt + (size_t)(bcol + 64 + r0) * K + k8;
  u16* Asl0 = As + tid * 8;
  u16* Asl1 = As + 2048 + tid * 8;
  u16* Bsl0 = Bs + tid * 8;
  u16* Bsl1 = Bs + 2048 + tid * 8;

  for (int k0 = 0; k0 < K; k0 += 32) {
    gll16(Ag0 + k0, Asl0);
    gll16(Ag1 + k0, Asl1);
    gll16(Bg0 + k0, Bsl0);
    gll16(Bg1 + k0, Bsl1);
    __syncthreads();
    bf16x8 a[4], b[4];
#pragma unroll
    for (int m = 0; m < 4; ++m)
      a[m] = *(const bf16x8*)&As[(wm * 64 + m * 16 + l15) * 32 + lg * 8];
#pragma unroll
    for (int n = 0; n < 4; ++n)
      b[n] = *(const bf16x8*)&Bs[(wn * 64 + n * 16 + l15) * 32 + lg * 8];
#pragma unroll
    for (int m = 0; m < 4; ++m)
#pragma unroll
      for (int n = 0; n < 4; ++n)
        acc[m][n] = MFMA(a[m], b[n], acc[m][n]);
    __syncthreads();
  }

#pragma unroll
  for (int m = 0; m < 4; ++m) {
    const int row = brow + wm * 64 + m * 16 + lg * 4;
#pragma unroll
    for (int n = 0; n < 4; ++n) {
      const int col = bcol + wn * 64 + n * 16 + l15;
#pragma unroll
      for (int r = 0; r < 4; ++r) {
        const float v = acc[m][n][r];
        if (F32OUT)
          ((float*)Cout)[(size_t)(row + r) * N + col] = v;
        else
          ((u16*)Cout)[(size_t)(row + r) * N + col] = f2b(v);
      }
    }
  }
}

// ---------------- fused causal flash attention (v4) ----------------------
// 512 blocks x 256 thr (4 waves). Each block: q-tile PAIR (k, 31-k), 64 rows
// each, processed sequentially -> EXACTLY 17 128-row KV tile-steps per block.
// 2 blocks/CU (80KB LDS each), whole grid co-resident, zero tail.
// Transposed PV (O^T), lane-local softmax stats, defer-max, double-buffered
// K (global_load_lds) and V^T (reg round-trip, issue-early/write-late).
__global__ __launch_bounds__(256, 2) void k_attn(const u16* __restrict__ qkv,
                                                 u16* __restrict__ y) {
  __shared__ u16 Kl[2][128 * 64];   // [t][d], swizzled sw(t)   32KB
  __shared__ u16 Vt[2][64 * 128];   // [d][t], swizzled sw(d)   32KB
  __shared__ u16 Pl[4][16 * 128];   // per-wave [q][t], sw(q)   16KB
  const int tid = threadIdx.x;
  const int lane = tid & 63;
  const int w = tid >> 6;
  const int l15 = lane & 15, lg = lane >> 4;

  // 8 XCDs x {4 heads x 16 pair-blocks}; all pair-blocks uniform (17 steps).
  const int lin = blockIdx.x;          // 0..511
  const int xcd = lin & 7;
  const int idx = lin >> 3;            // 0..63
  const int bh = xcd * 4 + (idx >> 4); // 0..31
  const int pidx = idx & 15;           // pair index
  const int b = bh >> 4, h = bh & 15;

  const u16* Qg = qkv + (size_t)(b * 2048) * 3072 + h * 64;
  const u16* Kg = Qg + 1024;
  const u16* Vg = Qg + 2048;

  const int g4 = (tid >> 3) * 4;       // V staging: first of 4 t-rows
  const int d8 = (tid & 7) * 8;        // V staging: first of 8 d-values

  for (int pass = 0; pass < 2; ++pass) {
    const int qi = pass ? (31 - pidx) : pidx;   // q-tile (64 rows)
    const int nt = (qi + 2) >> 1;               // # of 128-row KV tiles
    const int qw0 = qi * 64 + w * 16;
    const int qrow = qw0 + l15;

    // Q fragments (col q=l15, k=kd*32+lg*8), pre-scaled by 1/8*log2(e)
    bf16x8 aq[2];
#pragma unroll
    for (int kd = 0; kd < 2; ++kd) {
      bf16x8 v = *(const bf16x8*)&Qg[(size_t)(qw0 + l15) * 3072 + kd * 32 + lg * 8];
#pragma unroll
      for (int j = 0; j < 8; ++j)
        v[j] = (short)f2b(b2f((u16)v[j]) * 0.18033688011112042f);
      aq[kd] = v;
    }

    f32x4 acc[4] = {};     // O^T: col q=l15, row d=n*16+lg*4+r
    float mrun = -1e30f, lrun = 0.f;

    // --- prologue: stage tile 0 into buffer 0 ---
    {
#pragma unroll
      for (int p = 0; p < 4; ++p) {
        const int slot = p * 256 + tid;
        const int row = slot >> 3;
        const int colb = (slot & 7) * 16;
        gll16(Kg + (size_t)row * 3072 + ((colb ^ sw(row)) >> 1),
              (u16*)Kl[0] + slot * 8);
      }
      bf16x8 vl[4];
#pragma unroll
      for (int i = 0; i < 4; ++i)
        vl[i] = *(const bf16x8*)&Vg[(size_t)(g4 + i) * 3072 + d8];
#pragma unroll
      for (int j = 0; j < 8; ++j) {
        const int d = d8 + j;
        const u64 val = (u64)(u16)vl[0][j] | ((u64)(u16)vl[1][j] << 16) |
                        ((u64)(u16)vl[2][j] << 32) | ((u64)(u16)vl[3][j] << 48);
        *(u64*)((char*)Vt[0] + ((d * 256 + g4 * 2) ^ sw(d))) = val;
      }
    }
    __syncthreads();

    int cur = 0;
    for (int it = 0; it < nt; ++it) {
      const int t0 = it * 128;
      const bool more = (it + 1 < nt);
      bf16x8 vn[4];
      if (more) {
        const int tn = t0 + 128;
#pragma unroll
        for (int p = 0; p < 4; ++p) {
          const int slot = p * 256 + tid;
          const int row = slot >> 3;
          const int colb = (slot & 7) * 16;
          gll16(Kg + (size_t)(tn + row) * 3072 + ((colb ^ sw(row)) >> 1),
                (u16*)Kl[cur ^ 1] + slot * 8);
        }
#pragma unroll
        for (int i = 0; i < 4; ++i)
          vn[i] = *(const bf16x8*)&Vg[(size_t)(tn + g4 + i) * 3072 + d8];
      }

      // ---- S^T = K Q^T : lane holds t = n*16+lg*4+r, q = l15 ----
      f32x4 st[8];
#pragma unroll
      for (int n = 0; n < 8; ++n) {
        const int row = n * 16 + l15;
        const bf16x8 bk0 = *(const bf16x8*)((const char*)Kl[cur] +
                              ((row * 128 + 0 + lg * 16) ^ sw(row)));
        const bf16x8 bk1 = *(const bf16x8*)((const char*)Kl[cur] +
                              ((row * 128 + 64 + lg * 16) ^ sw(row)));
        f32x4 z = {};
        z = MFMA(bk0, aq[0], z);
        z = MFMA(bk1, aq[1], z);
        st[n] = z;
      }

      // ---- online softmax, stats lane-local at q = l15 ----
      float mx = -1e30f;
      if (it == nt - 1) {  // only the last tile can touch the diagonal
#pragma unroll
        for (int n = 0; n < 8; ++n)
#pragma unroll
          for (int r = 0; r < 4; ++r) {
            const int kkg = t0 + n * 16 + lg * 4 + r;
            float v = st[n][r];
            v = (kkg > qrow) ? -1e30f : v;
            st[n][r] = v;
            mx = fmaxf(mx, v);
          }
      } else {
#pragma unroll
        for (int n = 0; n < 8; ++n)
#pragma unroll
          for (int r = 0; r < 4; ++r) mx = fmaxf(mx, st[n][r]);
      }
      mx = fmaxf(mx, __shfl_xor(mx, 16));
      mx = fmaxf(mx, __shfl_xor(mx, 32));

      const float mo = mrun;
      const bool defer = __all(mx <= mo + 8.0f);
      const float mn = defer ? mo : fmaxf(mo, mx);
      float rs = 0.f;
#pragma unroll
      for (int n = 0; n < 8; ++n)
#pragma unroll
        for (int r = 0; r < 4; ++r) {
          const float p = exp2f(st[n][r] - mn);
          st[n][r] = p;
          rs += p;
        }
      rs += __shfl_xor(rs, 16);
      rs += __shfl_xor(rs, 32);
      if (defer) {
        lrun += rs;
      } else {
        const float sc = exp2f(mo - mn);
        lrun = lrun * sc + rs;
        mrun = mn;
#pragma unroll
        for (int n = 0; n < 4; ++n)
#pragma unroll
          for (int r = 0; r < 4; ++r) acc[n][r] *= sc;
      }

      // ---- write P[q=l15][t] packed u64 (min-conflict b64) ----
#pragma unroll
      for (int n = 0; n < 8; ++n) {
        const u64 pk = (u64)f2b(st[n][0]) | ((u64)f2b(st[n][1]) << 16) |
                       ((u64)f2b(st[n][2]) << 32) | ((u64)f2b(st[n][3]) << 48);
        *(u64*)((char*)Pl[w] + ((l15 * 256 + n * 32 + lg * 8) ^ sw(l15))) = pk;
      }

      // ---- O^T += V^T P ----
      bf16x8 pa[4];
#pragma unroll
      for (int kg = 0; kg < 4; ++kg)
        pa[kg] = *(const bf16x8*)((const char*)Pl[w] +
                     ((l15 * 256 + kg * 64 + lg * 16) ^ sw(l15)));
#pragma unroll
      for (int n = 0; n < 4; ++n) {
        const int d = n * 16 + l15;
#pragma unroll
        for (int kg = 0; kg < 4; ++kg) {
          const bf16x8 vb = *(const bf16x8*)((const char*)Vt[cur] +
                               ((d * 256 + kg * 64 + lg * 16) ^ sw(d)));
          acc[n] = MFMA(vb, pa[kg], acc[n]);
        }
      }

      // late half of async V stage: regs -> LDS buf^1
      if (more) {
#pragma unroll
        for (int j = 0; j < 8; ++j) {
          const int d = d8 + j;
          const u64 val = (u64)(u16)vn[0][j] | ((u64)(u16)vn[1][j] << 16) |
                          ((u64)(u16)vn[2][j] << 32) | ((u64)(u16)vn[3][j] << 48);
          *(u64*)((char*)Vt[cur ^ 1] + ((d * 256 + g4 * 2) ^ sw(d))) = val;
        }
      }
      __syncthreads();
      cur ^= 1;
    }

    // ---- epilogue: normalize (lane-local) and store y packed u64 ----
    const float linv = 1.0f / lrun;
    const size_t yrow = (size_t)(b * 2048 + qw0 + l15) * 1024 + h * 64;
#pragma unroll
    for (int n = 0; n < 4; ++n) {
      const u64 pk = (u64)f2b(acc[n][0] * linv) |
                     ((u64)f2b(acc[n][1] * linv) << 16) |
                     ((u64)f2b(acc[n][2] * linv) << 32) |
                     ((u64)f2b(acc[n][3] * linv) << 48);
      *(u64*)&y[yrow + n * 16 + lg * 4] = pk;
    }
  }
}

// ---------------- host launch ----------------
extern "C" void kernel_launch(void* const* d_in, const int* in_sizes, int n_in,
                              void* d_out, int out_size, void* d_ws, size_t ws_size,
                              hipStream_t stream) {
  const float* x  = (const float*)d_in[0];   // [2,2048,1024]
  const float* wa = (const float*)d_in[1];   // [1024,3072]
  const float* wp = (const float*)d_in[2];   // [1024,1024]
  float* out = (float*)d_out;                // [2,2048,1024] fp32

  u16* xb  = (u16*)d_ws;                 // [4096][1024] bf16
  u16* wat = xb + (size_t)4096 * 1024;   // [3072][1024] bf16 (w_attn^T)
  u16* wpt = wat + (size_t)3072 * 1024;  // [1024][1024] bf16 (w_proj^T)
  u16* qkv = wpt + (size_t)1024 * 1024;  // [4096][3072] bf16
  u16* yb  = qkv + (size_t)4096 * 3072;  // [4096][1024] bf16

  k_cvt<<<4096, 256, 0, stream>>>(x, xb, 4096 * 1024 / 4);
  k_trcvt<<<dim3(3072 / 64, 1024 / 64), 256, 0, stream>>>(wa, wat, 1024, 3072);
  k_trcvt<<<dim3(1024 / 64, 1024 / 64), 256, 0, stream>>>(wp, wpt, 1024, 1024);

  // qkv = x @ w_attn   (bf16 out)
  k_gemm<0><<<dim3(3072 / 128, 4096 / 128), 256, 0, stream>>>(xb, wat, qkv, 4096, 3072, 1024);

  // fused causal attention -> y [4096][1024] bf16
  k_attn<<<512, 256, 0, stream>>>(qkv, yb);

  // out = y @ w_proj   (fp32 out)
  k_gemm<1><<<dim3(1024 / 128, 4096 / 128), 256, 0, stream>>>(yb, wpt, out, 4096, 1024, 1024);
}